// Round 4
// baseline (195.404 us; speedup 1.0000x reference)
//
#include <hip/hip_runtime.h>
#include <hip/hip_bf16.h>

#define O_DIM 4096
#define I_DIM 4096
#define B_DIM 512
#define NQ ((O_DIM * I_DIM) / 4)     // 4,194,304 quads of 4 elements
#define MASK_GRID 2048
#define QPT (NQ / (MASK_GRID * 256)) // 8 quads per thread

typedef short bf16x8 __attribute__((ext_vector_type(8)));
typedef float f32x4 __attribute__((ext_vector_type(4)));

__device__ __forceinline__ unsigned short f2bf(float x) {
    return __builtin_bit_cast(unsigned short, __float2bfloat16(x));
}

// f64 tie resolution: matches the numpy f64 reference's argmax decisions.
// Lives ONLY in the cold fixup kernel / fallback kernel — never in the hot loop.
__device__ __forceinline__ int argmax3_f64(
    float lb, float lf, float lp, float u0, float u1, float u2)
{
    double d0 = (double)lb - log(-log((double)u0 + 1e-20) + 1e-20);
    double d1 = (double)lf - log(-log((double)u1 + 1e-20) + 1e-20);
    double d2 = (double)lp - log(-log((double)u2 + 1e-20) + 1e-20);
    int k = 0; double db = d0;
    if (d1 > db) { db = d1; k = 1; }
    if (d2 > db) { k = 2; }
    return k;
}

// ---------------------------------------------------------------------------
// Pass A: hot mask kernel. Pure f32, no calls, no divergent slow path.
// Writes wm quad + a per-quad tie-flag byte (bits 0..3). Manual 2-deep
// register pipeline: issue quad i+1's 7 float4 loads before processing quad i.
// ---------------------------------------------------------------------------
struct Quad { float4 b, f, p, w, n0, n1, n2; };

__device__ __forceinline__ void load_quad(
    const float* __restrict__ pb, const float* __restrict__ pf,
    const float* __restrict__ pp, const float* __restrict__ wts,
    const float* __restrict__ noise, int q, Quad& d)
{
    d.b = ((const float4*)pb)[q];
    d.f = ((const float4*)pf)[q];
    d.p = ((const float4*)pp)[q];
    d.w = ((const float4*)wts)[q];
    const float4* n = (const float4*)noise + (size_t)q * 3;
    d.n0 = n[0]; d.n1 = n[1]; d.n2 = n[2];
}

__device__ __forceinline__ void process_quad(
    const Quad& d, int q, unsigned short* __restrict__ wm,
    unsigned char* __restrict__ flags)
{
    float lb[4] = {d.b.x, d.b.y, d.b.z, d.b.w};
    float lf[4] = {d.f.x, d.f.y, d.f.z, d.f.w};
    float lp[4] = {d.p.x, d.p.y, d.p.z, d.p.w};
    float wv[4] = {d.w.x, d.w.y, d.w.z, d.w.w};
    float uu[12] = {d.n0.x,d.n0.y,d.n0.z,d.n0.w,
                    d.n1.x,d.n1.y,d.n1.z,d.n1.w,
                    d.n2.x,d.n2.y,d.n2.z,d.n2.w};
    unsigned short out[4];
    int tiemask = 0;
    #pragma unroll
    for (int j = 0; j < 4; ++j) {
        float u0 = uu[3*j+0], u1 = uu[3*j+1], u2 = uu[3*j+2];
        float t0 = lb[j] - __logf(-__logf(u0 + 1e-20f) + 1e-20f);
        float t1 = lf[j] - __logf(-__logf(u1 + 1e-20f) + 1e-20f);
        float t2 = lp[j] - __logf(-__logf(u2 + 1e-20f) + 1e-20f);
        int k = 0; float best = t0;
        if (t1 > best) { best = t1; k = 1; }
        if (t2 > best) { best = t2; k = 2; }
        float sec = (k == 0) ? fmaxf(t1, t2)
                  : (k == 1) ? fmaxf(t0, t2) : fmaxf(t0, t1);
        tiemask |= (best - sec < 1e-3f) ? (1 << j) : 0;
        float mw = (k == 0) ? wv[j] : (k == 1) ? -wv[j] : 0.0f;
        out[j] = f2bf(mw);
    }
    ushort4 o4 = {out[0], out[1], out[2], out[3]};
    ((ushort4*)wm)[q] = o4;
    flags[q] = (unsigned char)tiemask;   // unconditional: no memset needed
}

__global__ __launch_bounds__(256, 4) void mask_kernel(
    const float* __restrict__ wts,
    const float* __restrict__ pb, const float* __restrict__ pf,
    const float* __restrict__ pp, const float* __restrict__ noise,
    unsigned short* __restrict__ wm, unsigned char* __restrict__ flags)
{
    const int NTH = MASK_GRID * 256;
    const int t = blockIdx.x * 256 + threadIdx.x;
    Quad cur, nxt;
    load_quad(pb, pf, pp, wts, noise, t, cur);
    #pragma unroll
    for (int i = 0; i < QPT; ++i) {
        if (i + 1 < QPT) load_quad(pb, pf, pp, wts, noise, t + (i + 1) * NTH, nxt);
        process_quad(cur, t + i * NTH, wm, flags);
        if (i + 1 < QPT) cur = nxt;
    }
}

// ---------------------------------------------------------------------------
// Pass B: fixup. Scan flag bytes 16-at-a-time; ~0.4% of quads are flagged.
// For each flagged element, recompute the argmax in f64 and overwrite wm.
// ---------------------------------------------------------------------------
__global__ __launch_bounds__(256) void fixup_kernel(
    const float* __restrict__ wts,
    const float* __restrict__ pb, const float* __restrict__ pf,
    const float* __restrict__ pp, const float* __restrict__ noise,
    const unsigned char* __restrict__ flags, unsigned short* __restrict__ wm)
{
    int t = blockIdx.x * 256 + threadIdx.x;      // NQ/16 threads
    uint4 fv = ((const uint4*)flags)[t];
    if ((fv.x | fv.y | fv.z | fv.w) == 0) return;
    unsigned int wrd[4] = {fv.x, fv.y, fv.z, fv.w};
    #pragma unroll
    for (int wi = 0; wi < 4; ++wi) {
        unsigned int word = wrd[wi];
        while (word) {
            int bit = __ffs(word) - 1;
            word &= word - 1;
            int byteq = bit >> 3, j = bit & 7;   // j < 4 by construction
            int qd = t * 16 + wi * 4 + byteq;
            int idx = qd * 4 + j;
            float u0 = noise[(size_t)idx * 3 + 0];
            float u1 = noise[(size_t)idx * 3 + 1];
            float u2 = noise[(size_t)idx * 3 + 2];
            int k = argmax3_f64(pb[idx], pf[idx], pp[idx], u0, u1, u2);
            float wv = wts[idx];
            float mw = (k == 0) ? wv : (k == 1) ? -wv : 0.0f;
            wm[idx] = f2bf(mw);
        }
    }
}

// ---------------------------------------------------------------------------
// Fallback (ws too small for flags): known-passing single-pass kernel.
// ---------------------------------------------------------------------------
__global__ __launch_bounds__(256) void mask_kernel_fb(
    const float* __restrict__ wts,
    const float* __restrict__ pb, const float* __restrict__ pf,
    const float* __restrict__ pp, const float* __restrict__ noise,
    unsigned short* __restrict__ wm)
{
    const int total4 = NQ;
    int stride = gridDim.x * blockDim.x;
    for (int q = blockIdx.x * blockDim.x + threadIdx.x; q < total4; q += stride) {
        float4 b4 = ((const float4*)pb)[q];
        float4 f4 = ((const float4*)pf)[q];
        float4 p4 = ((const float4*)pp)[q];
        float4 w4 = ((const float4*)wts)[q];
        float4 n0 = ((const float4*)noise)[(long)q*3 + 0];
        float4 n1 = ((const float4*)noise)[(long)q*3 + 1];
        float4 n2 = ((const float4*)noise)[(long)q*3 + 2];
        float lb[4] = {b4.x, b4.y, b4.z, b4.w};
        float lf[4] = {f4.x, f4.y, f4.z, f4.w};
        float lp[4] = {p4.x, p4.y, p4.z, p4.w};
        float wv[4] = {w4.x, w4.y, w4.z, w4.w};
        float uu[12] = {n0.x,n0.y,n0.z,n0.w, n1.x,n1.y,n1.z,n1.w, n2.x,n2.y,n2.z,n2.w};
        unsigned short out[4];
        #pragma unroll
        for (int j = 0; j < 4; ++j) {
            float u0 = uu[3*j+0], u1 = uu[3*j+1], u2 = uu[3*j+2];
            float t0 = lb[j] - __logf(-__logf(u0 + 1e-20f) + 1e-20f);
            float t1 = lf[j] - __logf(-__logf(u1 + 1e-20f) + 1e-20f);
            float t2 = lp[j] - __logf(-__logf(u2 + 1e-20f) + 1e-20f);
            int k = 0; float best = t0;
            if (t1 > best) { best = t1; k = 1; }
            if (t2 > best) { best = t2; k = 2; }
            float sec = (k == 0) ? fmaxf(t1, t2)
                      : (k == 1) ? fmaxf(t0, t2) : fmaxf(t0, t1);
            if (best - sec < 1e-3f)
                k = argmax3_f64(lb[j], lf[j], lp[j], u0, u1, u2);
            float mw = (k == 0) ? wv[j] : (k == 1) ? -wv[j] : 0.0f;
            out[j] = f2bf(mw);
        }
        ushort4 o4 = {out[0], out[1], out[2], out[3]};
        ((ushort4*)wm)[q] = o4;
    }
}

// ---------------------------------------------------------------------------
// x (f32) -> bf16
// ---------------------------------------------------------------------------
__global__ __launch_bounds__(256) void cvt_kernel(
    const float* __restrict__ x, unsigned short* __restrict__ xb)
{
    const int total4 = (B_DIM * I_DIM) / 4;
    int stride = gridDim.x * blockDim.x;
    for (int q = blockIdx.x * blockDim.x + threadIdx.x; q < total4; q += stride) {
        float4 v = ((const float4*)x)[q];
        ushort4 o = {f2bf(v.x), f2bf(v.y), f2bf(v.z), f2bf(v.w)};
        ((ushort4*)xb)[q] = o;
    }
}

// ---------------------------------------------------------------------------
// GEMM: C[b][o] = sum_k xb[b][k] * wm[o][k] + bias[o]  (unchanged from R2)
// ---------------------------------------------------------------------------
#define BM 64
#define BN 64
#define BK 64
#define NT (I_DIM / BK)

__global__ __launch_bounds__(256, 2) void gemm_kernel(
    const unsigned short* __restrict__ A,   // xb [512][4096] bf16
    const unsigned short* __restrict__ Bw,  // wm [4096][4096] bf16
    const float* __restrict__ bias,
    float* __restrict__ C)
{
    __shared__ unsigned short Asm[2][BM * BK];
    __shared__ unsigned short Bsm[2][BN * BK];
    const int K = I_DIM;

    int tid = threadIdx.x;
    int w = tid >> 6, l = tid & 63;
    int bm0 = (blockIdx.x >> 6) * BM;
    int bn0 = (blockIdx.x & 63) * BN;
    int wr = w >> 1, wc = w & 1;
    int lrow = l & 15, lhi = l >> 4, swz = l & 7;

    int srow = l >> 3;
    int schunk = (l & 7) ^ srow;

    f32x4 acc[2][2] = {};

#define STAGE(buf, k0)                                                         \
    {                                                                          \
        _Pragma("unroll")                                                      \
        for (int j = 0; j < 2; ++j) {                                          \
            int rr = j * 32 + w * 8 + srow;                                    \
            const unsigned short* sa = &A[(size_t)(bm0 + rr) * K + (k0) + schunk * 8];  \
            const unsigned short* sb = &Bw[(size_t)(bn0 + rr) * K + (k0) + schunk * 8]; \
            __builtin_amdgcn_global_load_lds(                                  \
                (const __attribute__((address_space(1))) void*)sa,             \
                (__attribute__((address_space(3))) void*)&Asm[buf][(j * 32 + w * 8) * BK], \
                16, 0, 0);                                                     \
            __builtin_amdgcn_global_load_lds(                                  \
                (const __attribute__((address_space(1))) void*)sb,             \
                (__attribute__((address_space(3))) void*)&Bsm[buf][(j * 32 + w * 8) * BK], \
                16, 0, 0);                                                     \
        }                                                                      \
    }

    STAGE(0, 0);
    __syncthreads();

    for (int t = 0; t < NT; ++t) {
        int cur = t & 1;
        if (t + 1 < NT) STAGE(cur ^ 1, (t + 1) * BK);

        bf16x8 a[2][2], b[2][2];
        #pragma unroll
        for (int kk = 0; kk < 2; ++kk) {
            #pragma unroll
            for (int m = 0; m < 2; ++m)
                a[kk][m] = *(const bf16x8*)&Asm[cur][(wr * 32 + m * 16 + lrow) * BK +
                                                     (((kk * 4 + lhi) ^ swz) * 8)];
            #pragma unroll
            for (int n = 0; n < 2; ++n)
                b[kk][n] = *(const bf16x8*)&Bsm[cur][(wc * 32 + n * 16 + lrow) * BK +
                                                     (((kk * 4 + lhi) ^ swz) * 8)];
        }
        #pragma unroll
        for (int kk = 0; kk < 2; ++kk)
            #pragma unroll
            for (int m = 0; m < 2; ++m)
                #pragma unroll
                for (int n = 0; n < 2; ++n)
                    acc[m][n] = __builtin_amdgcn_mfma_f32_16x16x32_bf16(
                        a[kk][m], b[kk][n], acc[m][n], 0, 0, 0);

        __syncthreads();
    }
#undef STAGE

    int crow0 = bm0 + wr * 32 + lhi * 4;
    #pragma unroll
    for (int n = 0; n < 2; ++n) {
        int col = bn0 + wc * 32 + n * 16 + lrow;
        float bv = bias[col];
        #pragma unroll
        for (int m = 0; m < 2; ++m)
            #pragma unroll
            for (int r = 0; r < 4; ++r)
                C[(size_t)(crow0 + m * 16 + r) * O_DIM + col] = acc[m][n][r] + bv;
    }
}

extern "C" void kernel_launch(void* const* d_in, const int* in_sizes, int n_in,
                              void* d_out, int out_size, void* d_ws, size_t ws_size,
                              hipStream_t stream) {
    const float* x    = (const float*)d_in[0];
    const float* wts  = (const float*)d_in[1];
    const float* bias = (const float*)d_in[2];
    const float* pb   = (const float*)d_in[3];
    const float* pf   = (const float*)d_in[4];
    const float* pp   = (const float*)d_in[5];
    const float* un   = (const float*)d_in[6];
    float* out = (float*)d_out;

    unsigned short* wm = (unsigned short*)d_ws;              // 32 MB bf16 masked W
    unsigned short* xb = wm + (size_t)O_DIM * I_DIM;         // 4 MB bf16 x
    size_t flags_off = (size_t)O_DIM * I_DIM * 2 + (size_t)B_DIM * I_DIM * 2;
    unsigned char* flags = (unsigned char*)d_ws + flags_off; // 4 MB flag bytes

    if (ws_size >= flags_off + (size_t)NQ) {
        mask_kernel<<<MASK_GRID, 256, 0, stream>>>(wts, pb, pf, pp, un, wm, flags);
        fixup_kernel<<<NQ / 16 / 256, 256, 0, stream>>>(wts, pb, pf, pp, un, flags, wm);
    } else {
        mask_kernel_fb<<<2048, 256, 0, stream>>>(wts, pb, pf, pp, un, wm);
    }
    cvt_kernel<<<512, 256, 0, stream>>>(x, xb);
    gemm_kernel<<<dim3((O_DIM / BN) * (B_DIM / BM)), 256, 0, stream>>>(xb, wm, bias, out);
}

// Round 5
// 167.655 us; speedup vs baseline: 1.1655x; 1.1655x over previous
//
#include <hip/hip_runtime.h>
#include <hip/hip_bf16.h>

#define O_DIM 4096
#define I_DIM 4096
#define B_DIM 512
#define NQ ((O_DIM * I_DIM) / 4)     // 4,194,304 quads of 4 elements
#define MASK_GRID 2048
#define QPT (NQ / (MASK_GRID * 256)) // 8 quads per thread

typedef short bf16x8 __attribute__((ext_vector_type(8)));
typedef float f32x4 __attribute__((ext_vector_type(4)));

__device__ __forceinline__ unsigned short f2bf(float x) {
    return __builtin_bit_cast(unsigned short, __float2bfloat16(x));
}

// f64 tie resolution: replicates the numpy f64 reference formula exactly.
// Rare (margin < 2e-3 in log2 units); inlined, one copy per j-loop.
__device__ __forceinline__ int argmax3_f64(
    float lb, float lf, float lp, float u0, float u1, float u2)
{
    double d0 = (double)lb - log(-log((double)u0 + 1e-20) + 1e-20);
    double d1 = (double)lf - log(-log((double)u1 + 1e-20) + 1e-20);
    double d2 = (double)lp - log(-log((double)u2 + 1e-20) + 1e-20);
    int k = 0; double db = d0;
    if (d1 > db) { db = d1; k = 1; }
    if (d2 > db) { k = 2; }
    return k;
}

// Base-2 monotone transform of t = l - ln(-ln(u+eps)+eps):
//   E = -ln(u+eps)+eps = fma(log2(u+eps), -ln2, eps);  s = l/ln2 - log2(E)
// Same ordering as t (division by ln2); 2 trans + 3 VALU.
__device__ __forceinline__ float score2(float l, float u) {
    const float INV_LN2 = 1.44269504088896341f;
    const float LN2 = 0.69314718055994531f;
    float lg = __log2f(u + 1e-20f);
    float E  = __builtin_fmaf(lg, -LN2, 1e-20f);
    return __builtin_fmaf(l, INV_LN2, -__log2f(E));
}

// ---------------------------------------------------------------------------
// Mask kernel: gumbel-argmax over 3 states, masked weights -> bf16.
// Noise (48B per lane-quad, the only badly-strided stream) is fetched
// PERFECTLY COALESCED via 3 global_load_lds DMAs into a wave-private LDS
// region, then read back per-lane (stride-48 ds_read: 8 visits/bank,
// conflict-free). No __syncthreads: wave-private region, per-wave
// s_waitcnt vmcnt(0) is the only sync. probs/wts stay reg-loaded (stride-16).
// ---------------------------------------------------------------------------
__global__ __launch_bounds__(256) void mask_kernel(
    const float* __restrict__ wts,
    const float* __restrict__ pb, const float* __restrict__ pf,
    const float* __restrict__ pp, const float* __restrict__ noise,
    unsigned short* __restrict__ wm)
{
    __shared__ float4 nbuf[4][192];          // 12 KB: 3 KB per wave
    const int NTH = MASK_GRID * 256;
    int tid = threadIdx.x;
    int w = tid >> 6, L = tid & 63;
    const char* noise_b = (const char*)noise;

    #pragma unroll 1
    for (int i = 0; i < QPT; ++i) {
        int q0 = blockIdx.x * 256 + w * 64 + i * NTH;  // wave's first quad
        int q  = q0 + L;                               // this lane's quad

        // coalesced reg loads (stride-16: perfect)
        float4 b4 = ((const float4*)pb)[q];
        float4 f4 = ((const float4*)pf)[q];
        float4 p4 = ((const float4*)pp)[q];
        float4 w4 = ((const float4*)wts)[q];

        // noise: 3 coalesced global->LDS DMAs covering the wave's 3 KB
        #pragma unroll
        for (int n = 0; n < 3; ++n) {
            const char* sp = noise_b + (size_t)q0 * 48 + n * 1024 + L * 16;
            __builtin_amdgcn_global_load_lds(
                (const __attribute__((address_space(1))) void*)sp,
                (__attribute__((address_space(3))) void*)&nbuf[w][n * 64],
                16, 0, 0);
        }
        asm volatile("s_waitcnt vmcnt(0)" ::: "memory");
        __builtin_amdgcn_sched_barrier(0);

        float4 na = nbuf[w][3 * L + 0];
        float4 nb = nbuf[w][3 * L + 1];
        float4 nc = nbuf[w][3 * L + 2];
        asm volatile("s_waitcnt lgkmcnt(0)" ::: "memory");  // reads done before
        __builtin_amdgcn_sched_barrier(0);                  // next iter's DMA

        float U[4][3] = {{na.x, na.y, na.z}, {na.w, nb.x, nb.y},
                         {nb.z, nb.w, nc.x}, {nc.y, nc.z, nc.w}};
        float lb[4] = {b4.x, b4.y, b4.z, b4.w};
        float lf[4] = {f4.x, f4.y, f4.z, f4.w};
        float lp[4] = {p4.x, p4.y, p4.z, p4.w};
        float wv[4] = {w4.x, w4.y, w4.z, w4.w};

        unsigned short out[4];
        int tiemask = 0;
        #pragma unroll
        for (int j = 0; j < 4; ++j) {
            float s0 = score2(lb[j], U[j][0]);
            float s1 = score2(lf[j], U[j][1]);
            float s2 = score2(lp[j], U[j][2]);
            int k = 0; float best = s0;
            if (s1 > best) { best = s1; k = 1; }
            if (s2 > best) { best = s2; k = 2; }
            float sec = (k == 0) ? fmaxf(s1, s2)
                      : (k == 1) ? fmaxf(s0, s2) : fmaxf(s0, s1);
            tiemask |= (best - sec < 2e-3f) ? (1 << j) : 0;
            float mw = (k == 0) ? wv[j] : (k == 1) ? -wv[j] : 0.0f;
            out[j] = f2bf(mw);
        }
        if (__builtin_expect(tiemask != 0, 0)) {   // rare f64 re-resolve
            #pragma unroll
            for (int j = 0; j < 4; ++j)
                if (tiemask & (1 << j)) {
                    int k = argmax3_f64(lb[j], lf[j], lp[j],
                                        U[j][0], U[j][1], U[j][2]);
                    float mw = (k == 0) ? wv[j] : (k == 1) ? -wv[j] : 0.0f;
                    out[j] = f2bf(mw);
                }
        }
        ushort4 o4 = {out[0], out[1], out[2], out[3]};
        ((ushort4*)wm)[q] = o4;
    }
}

// ---------------------------------------------------------------------------
// x (f32) -> bf16
// ---------------------------------------------------------------------------
__global__ __launch_bounds__(256) void cvt_kernel(
    const float* __restrict__ x, unsigned short* __restrict__ xb)
{
    const int total4 = (B_DIM * I_DIM) / 4;
    int stride = gridDim.x * blockDim.x;
    for (int q = blockIdx.x * blockDim.x + threadIdx.x; q < total4; q += stride) {
        float4 v = ((const float4*)x)[q];
        ushort4 o = {f2bf(v.x), f2bf(v.y), f2bf(v.z), f2bf(v.w)};
        ((ushort4*)xb)[q] = o;
    }
}

// ---------------------------------------------------------------------------
// GEMM: C[b][o] = sum_k xb[b][k] * wm[o][k] + bias[o]  (unchanged from R2)
// ---------------------------------------------------------------------------
#define BM 64
#define BN 64
#define BK 64
#define NT (I_DIM / BK)

__global__ __launch_bounds__(256, 2) void gemm_kernel(
    const unsigned short* __restrict__ A,   // xb [512][4096] bf16
    const unsigned short* __restrict__ Bw,  // wm [4096][4096] bf16
    const float* __restrict__ bias,
    float* __restrict__ C)
{
    __shared__ unsigned short Asm[2][BM * BK];
    __shared__ unsigned short Bsm[2][BN * BK];
    const int K = I_DIM;

    int tid = threadIdx.x;
    int w = tid >> 6, l = tid & 63;
    int bm0 = (blockIdx.x >> 6) * BM;
    int bn0 = (blockIdx.x & 63) * BN;
    int wr = w >> 1, wc = w & 1;
    int lrow = l & 15, lhi = l >> 4, swz = l & 7;

    int srow = l >> 3;
    int schunk = (l & 7) ^ srow;

    f32x4 acc[2][2] = {};

#define STAGE(buf, k0)                                                         \
    {                                                                          \
        _Pragma("unroll")                                                      \
        for (int j = 0; j < 2; ++j) {                                          \
            int rr = j * 32 + w * 8 + srow;                                    \
            const unsigned short* sa = &A[(size_t)(bm0 + rr) * K + (k0) + schunk * 8];  \
            const unsigned short* sb = &Bw[(size_t)(bn0 + rr) * K + (k0) + schunk * 8]; \
            __builtin_amdgcn_global_load_lds(                                  \
                (const __attribute__((address_space(1))) void*)sa,             \
                (__attribute__((address_space(3))) void*)&Asm[buf][(j * 32 + w * 8) * BK], \
                16, 0, 0);                                                     \
            __builtin_amdgcn_global_load_lds(                                  \
                (const __attribute__((address_space(1))) void*)sb,             \
                (__attribute__((address_space(3))) void*)&Bsm[buf][(j * 32 + w * 8) * BK], \
                16, 0, 0);                                                     \
        }                                                                      \
    }

    STAGE(0, 0);
    __syncthreads();

    for (int t = 0; t < NT; ++t) {
        int cur = t & 1;
        if (t + 1 < NT) STAGE(cur ^ 1, (t + 1) * BK);

        bf16x8 a[2][2], b[2][2];
        #pragma unroll
        for (int kk = 0; kk < 2; ++kk) {
            #pragma unroll
            for (int m = 0; m < 2; ++m)
                a[kk][m] = *(const bf16x8*)&Asm[cur][(wr * 32 + m * 16 + lrow) * BK +
                                                     (((kk * 4 + lhi) ^ swz) * 8)];
            #pragma unroll
            for (int n = 0; n < 2; ++n)
                b[kk][n] = *(const bf16x8*)&Bsm[cur][(wc * 32 + n * 16 + lrow) * BK +
                                                     (((kk * 4 + lhi) ^ swz) * 8)];
        }
        #pragma unroll
        for (int kk = 0; kk < 2; ++kk)
            #pragma unroll
            for (int m = 0; m < 2; ++m)
                #pragma unroll
                for (int n = 0; n < 2; ++n)
                    acc[m][n] = __builtin_amdgcn_mfma_f32_16x16x32_bf16(
                        a[kk][m], b[kk][n], acc[m][n], 0, 0, 0);

        __syncthreads();
    }
#undef STAGE

    int crow0 = bm0 + wr * 32 + lhi * 4;
    #pragma unroll
    for (int n = 0; n < 2; ++n) {
        int col = bn0 + wc * 32 + n * 16 + lrow;
        float bv = bias[col];
        #pragma unroll
        for (int m = 0; m < 2; ++m)
            #pragma unroll
            for (int r = 0; r < 4; ++r)
                C[(size_t)(crow0 + m * 16 + r) * O_DIM + col] = acc[m][n][r] + bv;
    }
}

extern "C" void kernel_launch(void* const* d_in, const int* in_sizes, int n_in,
                              void* d_out, int out_size, void* d_ws, size_t ws_size,
                              hipStream_t stream) {
    const float* x    = (const float*)d_in[0];
    const float* wts  = (const float*)d_in[1];
    const float* bias = (const float*)d_in[2];
    const float* pb   = (const float*)d_in[3];
    const float* pf   = (const float*)d_in[4];
    const float* pp   = (const float*)d_in[5];
    const float* un   = (const float*)d_in[6];
    float* out = (float*)d_out;

    unsigned short* wm = (unsigned short*)d_ws;              // 32 MB bf16 masked W
    unsigned short* xb = wm + (size_t)O_DIM * I_DIM;         // 4 MB bf16 x

    mask_kernel<<<MASK_GRID, 256, 0, stream>>>(wts, pb, pf, pp, un, wm);
    cvt_kernel<<<512, 256, 0, stream>>>(x, xb);
    gemm_kernel<<<dim3((O_DIM / BN) * (B_DIM / BM)), 256, 0, stream>>>(xb, wm, bias, out);
}

// Round 6
// 164.255 us; speedup vs baseline: 1.1896x; 1.0207x over previous
//
#include <hip/hip_runtime.h>
#include <hip/hip_bf16.h>

#define O_DIM 4096
#define I_DIM 4096
#define B_DIM 512

typedef short bf16x8 __attribute__((ext_vector_type(8)));
typedef float f32x4 __attribute__((ext_vector_type(4)));

__device__ __forceinline__ unsigned short f2bf(float x) {
    return __builtin_bit_cast(unsigned short, __float2bfloat16(x));
}

// ---------------------------------------------------------------------------
// Mask kernel — R1-exact form (proven ~103 us timed / 4.7 TB/s logical,
// which is ~ the 7-stream streaming floor; R2-R5 "optimizations" all
// regressed it). Grid-stride, 7x float4 loads, f32 fast path with __logf,
// inline f64 re-resolve when the winning margin < 1e-3 (matches the f64
// numpy reference's argmax decisions; passed at absmax 0.0459 in R1).
// ---------------------------------------------------------------------------
__global__ __launch_bounds__(256) void mask_kernel(
    const float* __restrict__ wts,
    const float* __restrict__ pb, const float* __restrict__ pf,
    const float* __restrict__ pp, const float* __restrict__ noise,
    unsigned short* __restrict__ wm)
{
    const int total4 = (O_DIM * I_DIM) / 4;
    int stride = gridDim.x * blockDim.x;
    for (int q = blockIdx.x * blockDim.x + threadIdx.x; q < total4; q += stride) {
        float4 b4 = ((const float4*)pb)[q];
        float4 f4 = ((const float4*)pf)[q];
        float4 p4 = ((const float4*)pp)[q];
        float4 w4 = ((const float4*)wts)[q];
        float4 n0 = ((const float4*)noise)[(long)q*3 + 0];
        float4 n1 = ((const float4*)noise)[(long)q*3 + 1];
        float4 n2 = ((const float4*)noise)[(long)q*3 + 2];
        float lb[4] = {b4.x, b4.y, b4.z, b4.w};
        float lf[4] = {f4.x, f4.y, f4.z, f4.w};
        float lp[4] = {p4.x, p4.y, p4.z, p4.w};
        float wv[4] = {w4.x, w4.y, w4.z, w4.w};
        float uu[12] = {n0.x,n0.y,n0.z,n0.w, n1.x,n1.y,n1.z,n1.w, n2.x,n2.y,n2.z,n2.w};
        unsigned short out[4];
        #pragma unroll
        for (int j = 0; j < 4; ++j) {
            float u0 = uu[3*j+0], u1 = uu[3*j+1], u2 = uu[3*j+2];
            float t0 = lb[j] - __logf(-__logf(u0 + 1e-20f) + 1e-20f);
            float t1 = lf[j] - __logf(-__logf(u1 + 1e-20f) + 1e-20f);
            float t2 = lp[j] - __logf(-__logf(u2 + 1e-20f) + 1e-20f);
            int k = 0; float best = t0;
            if (t1 > best) { best = t1; k = 1; }
            if (t2 > best) { best = t2; k = 2; }
            float sec = (k == 0) ? fmaxf(t1, t2)
                      : (k == 1) ? fmaxf(t0, t2) : fmaxf(t0, t1);
            if (best - sec < 1e-3f) {  // near-tie: resolve in f64 (rare)
                double d0 = (double)lb[j] - log(-log((double)u0 + 1e-20) + 1e-20);
                double d1 = (double)lf[j] - log(-log((double)u1 + 1e-20) + 1e-20);
                double d2 = (double)lp[j] - log(-log((double)u2 + 1e-20) + 1e-20);
                k = 0; double db = d0;
                if (d1 > db) { db = d1; k = 1; }
                if (d2 > db) { k = 2; }
            }
            float mw = (k == 0) ? wv[j] : (k == 1) ? -wv[j] : 0.0f;
            out[j] = f2bf(mw);
        }
        ushort4 o4 = {out[0], out[1], out[2], out[3]};
        ((ushort4*)wm)[q] = o4;
    }
}

// ---------------------------------------------------------------------------
// x (f32) -> bf16
// ---------------------------------------------------------------------------
__global__ __launch_bounds__(256) void cvt_kernel(
    const float* __restrict__ x, unsigned short* __restrict__ xb)
{
    const int total4 = (B_DIM * I_DIM) / 4;
    int stride = gridDim.x * blockDim.x;
    for (int q = blockIdx.x * blockDim.x + threadIdx.x; q < total4; q += stride) {
        float4 v = ((const float4*)x)[q];
        ushort4 o = {f2bf(v.x), f2bf(v.y), f2bf(v.z), f2bf(v.w)};
        ((ushort4*)xb)[q] = o;
    }
}

// ---------------------------------------------------------------------------
// GEMM: C[b][o] = sum_k xb[b][k] * wm[o][k] + bias[o]  (R2 version, proven)
// BM=BN=64, BK=64, 4 waves (2x2), double-buffered LDS via global_load_lds
// width=16, XOR-swizzle on global source + ds_read (rule #21).
// ---------------------------------------------------------------------------
#define BM 64
#define BN 64
#define BK 64
#define NT (I_DIM / BK)

__global__ __launch_bounds__(256, 2) void gemm_kernel(
    const unsigned short* __restrict__ A,   // xb [512][4096] bf16
    const unsigned short* __restrict__ Bw,  // wm [4096][4096] bf16
    const float* __restrict__ bias,
    float* __restrict__ C)
{
    __shared__ unsigned short Asm[2][BM * BK];
    __shared__ unsigned short Bsm[2][BN * BK];
    const int K = I_DIM;

    int tid = threadIdx.x;
    int w = tid >> 6, l = tid & 63;
    int bm0 = (blockIdx.x >> 6) * BM;
    int bn0 = (blockIdx.x & 63) * BN;
    int wr = w >> 1, wc = w & 1;
    int lrow = l & 15, lhi = l >> 4, swz = l & 7;

    int srow = l >> 3;
    int schunk = (l & 7) ^ srow;

    f32x4 acc[2][2] = {};

#define STAGE(buf, k0)                                                         \
    {                                                                          \
        _Pragma("unroll")                                                      \
        for (int j = 0; j < 2; ++j) {                                          \
            int rr = j * 32 + w * 8 + srow;                                    \
            const unsigned short* sa = &A[(size_t)(bm0 + rr) * K + (k0) + schunk * 8];  \
            const unsigned short* sb = &Bw[(size_t)(bn0 + rr) * K + (k0) + schunk * 8]; \
            __builtin_amdgcn_global_load_lds(                                  \
                (const __attribute__((address_space(1))) void*)sa,             \
                (__attribute__((address_space(3))) void*)&Asm[buf][(j * 32 + w * 8) * BK], \
                16, 0, 0);                                                     \
            __builtin_amdgcn_global_load_lds(                                  \
                (const __attribute__((address_space(1))) void*)sb,             \
                (__attribute__((address_space(3))) void*)&Bsm[buf][(j * 32 + w * 8) * BK], \
                16, 0, 0);                                                     \
        }                                                                      \
    }

    STAGE(0, 0);
    __syncthreads();

    for (int t = 0; t < NT; ++t) {
        int cur = t & 1;
        if (t + 1 < NT) STAGE(cur ^ 1, (t + 1) * BK);

        bf16x8 a[2][2], b[2][2];
        #pragma unroll
        for (int kk = 0; kk < 2; ++kk) {
            #pragma unroll
            for (int m = 0; m < 2; ++m)
                a[kk][m] = *(const bf16x8*)&Asm[cur][(wr * 32 + m * 16 + lrow) * BK +
                                                     (((kk * 4 + lhi) ^ swz) * 8)];
            #pragma unroll
            for (int n = 0; n < 2; ++n)
                b[kk][n] = *(const bf16x8*)&Bsm[cur][(wc * 32 + n * 16 + lrow) * BK +
                                                     (((kk * 4 + lhi) ^ swz) * 8)];
        }
        #pragma unroll
        for (int kk = 0; kk < 2; ++kk)
            #pragma unroll
            for (int m = 0; m < 2; ++m)
                #pragma unroll
                for (int n = 0; n < 2; ++n)
                    acc[m][n] = __builtin_amdgcn_mfma_f32_16x16x32_bf16(
                        a[kk][m], b[kk][n], acc[m][n], 0, 0, 0);

        __syncthreads();
    }
#undef STAGE

    int crow0 = bm0 + wr * 32 + lhi * 4;
    #pragma unroll
    for (int n = 0; n < 2; ++n) {
        int col = bn0 + wc * 32 + n * 16 + lrow;
        float bv = bias[col];
        #pragma unroll
        for (int m = 0; m < 2; ++m)
            #pragma unroll
            for (int r = 0; r < 4; ++r)
                C[(size_t)(crow0 + m * 16 + r) * O_DIM + col] = acc[m][n][r] + bv;
    }
}

extern "C" void kernel_launch(void* const* d_in, const int* in_sizes, int n_in,
                              void* d_out, int out_size, void* d_ws, size_t ws_size,
                              hipStream_t stream) {
    const float* x    = (const float*)d_in[0];
    const float* wts  = (const float*)d_in[1];
    const float* bias = (const float*)d_in[2];
    const float* pb   = (const float*)d_in[3];
    const float* pf   = (const float*)d_in[4];
    const float* pp   = (const float*)d_in[5];
    const float* un   = (const float*)d_in[6];
    float* out = (float*)d_out;

    unsigned short* wm = (unsigned short*)d_ws;              // 32 MB bf16 masked W
    unsigned short* xb = wm + (size_t)O_DIM * I_DIM;         // 4 MB bf16 x

    mask_kernel<<<2048, 256, 0, stream>>>(wts, pb, pf, pp, un, wm);
    cvt_kernel<<<512, 256, 0, stream>>>(x, xb);
    gemm_kernel<<<dim3((O_DIM / BN) * (B_DIM / BM)), 256, 0, stream>>>(xb, wm, bias, out);
}

// Round 7
// 149.672 us; speedup vs baseline: 1.3055x; 1.0974x over previous
//
#include <hip/hip_runtime.h>
#include <hip/hip_bf16.h>

#define O_DIM 4096
#define I_DIM 4096
#define B_DIM 512

typedef short bf16x8 __attribute__((ext_vector_type(8)));
typedef float f32x4 __attribute__((ext_vector_type(4)));

__device__ __forceinline__ unsigned short f2bf(float x) {
    return __builtin_bit_cast(unsigned short, __float2bfloat16(x));
}

// ---------------------------------------------------------------------------
// Mask kernel — R1-exact (timed ~103 us = 4.7 TB/s logical; near the
// 7-stream floor. R3-R5 variants all failed to beat it; rocprof rows for
// this kernel are cold-L3 replay artifacts, ignore them).
// ---------------------------------------------------------------------------
__global__ __launch_bounds__(256) void mask_kernel(
    const float* __restrict__ wts,
    const float* __restrict__ pb, const float* __restrict__ pf,
    const float* __restrict__ pp, const float* __restrict__ noise,
    unsigned short* __restrict__ wm)
{
    const int total4 = (O_DIM * I_DIM) / 4;
    int stride = gridDim.x * blockDim.x;
    for (int q = blockIdx.x * blockDim.x + threadIdx.x; q < total4; q += stride) {
        float4 b4 = ((const float4*)pb)[q];
        float4 f4 = ((const float4*)pf)[q];
        float4 p4 = ((const float4*)pp)[q];
        float4 w4 = ((const float4*)wts)[q];
        float4 n0 = ((const float4*)noise)[(long)q*3 + 0];
        float4 n1 = ((const float4*)noise)[(long)q*3 + 1];
        float4 n2 = ((const float4*)noise)[(long)q*3 + 2];
        float lb[4] = {b4.x, b4.y, b4.z, b4.w};
        float lf[4] = {f4.x, f4.y, f4.z, f4.w};
        float lp[4] = {p4.x, p4.y, p4.z, p4.w};
        float wv[4] = {w4.x, w4.y, w4.z, w4.w};
        float uu[12] = {n0.x,n0.y,n0.z,n0.w, n1.x,n1.y,n1.z,n1.w, n2.x,n2.y,n2.z,n2.w};
        unsigned short out[4];
        #pragma unroll
        for (int j = 0; j < 4; ++j) {
            float u0 = uu[3*j+0], u1 = uu[3*j+1], u2 = uu[3*j+2];
            float t0 = lb[j] - __logf(-__logf(u0 + 1e-20f) + 1e-20f);
            float t1 = lf[j] - __logf(-__logf(u1 + 1e-20f) + 1e-20f);
            float t2 = lp[j] - __logf(-__logf(u2 + 1e-20f) + 1e-20f);
            int k = 0; float best = t0;
            if (t1 > best) { best = t1; k = 1; }
            if (t2 > best) { best = t2; k = 2; }
            float sec = (k == 0) ? fmaxf(t1, t2)
                      : (k == 1) ? fmaxf(t0, t2) : fmaxf(t0, t1);
            if (best - sec < 1e-3f) {  // near-tie: resolve in f64 (rare)
                double d0 = (double)lb[j] - log(-log((double)u0 + 1e-20) + 1e-20);
                double d1 = (double)lf[j] - log(-log((double)u1 + 1e-20) + 1e-20);
                double d2 = (double)lp[j] - log(-log((double)u2 + 1e-20) + 1e-20);
                k = 0; double db = d0;
                if (d1 > db) { db = d1; k = 1; }
                if (d2 > db) { k = 2; }
            }
            float mw = (k == 0) ? wv[j] : (k == 1) ? -wv[j] : 0.0f;
            out[j] = f2bf(mw);
        }
        ushort4 o4 = {out[0], out[1], out[2], out[3]};
        ((ushort4*)wm)[q] = o4;
    }
}

// ---------------------------------------------------------------------------
// x (f32) -> bf16
// ---------------------------------------------------------------------------
__global__ __launch_bounds__(256) void cvt_kernel(
    const float* __restrict__ x, unsigned short* __restrict__ xb)
{
    const int total4 = (B_DIM * I_DIM) / 4;
    int stride = gridDim.x * blockDim.x;
    for (int q = blockIdx.x * blockDim.x + threadIdx.x; q < total4; q += stride) {
        float4 v = ((const float4*)x)[q];
        ushort4 o = {f2bf(v.x), f2bf(v.y), f2bf(v.z), f2bf(v.w)};
        ((ushort4*)xb)[q] = o;
    }
}

// ---------------------------------------------------------------------------
// GEMM with single-dispatch split-K. nphase=2: 1024 blocks (4/CU), phase p
// computes K in [p*2048, (p+1)*2048); partial0 -> C0 (=d_out, raw),
// partial1 -> C1 (=ws). Staging/swizzle identical to the proven R2 kernel.
// ---------------------------------------------------------------------------
#define BM 64
#define BN 64
#define BK 64

__global__ __launch_bounds__(256, 2) void gemm_kernel(
    const unsigned short* __restrict__ A,   // xb [512][4096] bf16
    const unsigned short* __restrict__ Bw,  // wm [4096][4096] bf16
    float* __restrict__ C0, float* __restrict__ C1, int nphase)
{
    __shared__ unsigned short Asm[2][BM * BK];
    __shared__ unsigned short Bsm[2][BN * BK];
    const int K = I_DIM;

    int idx = blockIdx.x;
    int kphase = (nphase == 2) ? (idx & 1) : 0;
    int tb     = (nphase == 2) ? (idx >> 1) : idx;
    int kbeg   = kphase * (K / nphase);
    int nt     = (K / nphase) / BK;
    float* __restrict__ Ct = kphase ? C1 : C0;

    int tid = threadIdx.x;
    int w = tid >> 6, l = tid & 63;
    int bm0 = (tb >> 6) * BM;
    int bn0 = (tb & 63) * BN;
    int wr = w >> 1, wc = w & 1;
    int lrow = l & 15, lhi = l >> 4, swz = l & 7;

    int srow = l >> 3;
    int schunk = (l & 7) ^ srow;

    f32x4 acc[2][2] = {};

#define STAGE(buf, k0)                                                         \
    {                                                                          \
        _Pragma("unroll")                                                      \
        for (int j = 0; j < 2; ++j) {                                          \
            int rr = j * 32 + w * 8 + srow;                                    \
            const unsigned short* sa = &A[(size_t)(bm0 + rr) * K + (k0) + schunk * 8];  \
            const unsigned short* sb = &Bw[(size_t)(bn0 + rr) * K + (k0) + schunk * 8]; \
            __builtin_amdgcn_global_load_lds(                                  \
                (const __attribute__((address_space(1))) void*)sa,             \
                (__attribute__((address_space(3))) void*)&Asm[buf][(j * 32 + w * 8) * BK], \
                16, 0, 0);                                                     \
            __builtin_amdgcn_global_load_lds(                                  \
                (const __attribute__((address_space(1))) void*)sb,             \
                (__attribute__((address_space(3))) void*)&Bsm[buf][(j * 32 + w * 8) * BK], \
                16, 0, 0);                                                     \
        }                                                                      \
    }

    STAGE(0, kbeg);
    __syncthreads();

    for (int t = 0; t < nt; ++t) {
        int cur = t & 1;
        if (t + 1 < nt) STAGE(cur ^ 1, kbeg + (t + 1) * BK);

        bf16x8 a[2][2], b[2][2];
        #pragma unroll
        for (int kk = 0; kk < 2; ++kk) {
            #pragma unroll
            for (int m = 0; m < 2; ++m)
                a[kk][m] = *(const bf16x8*)&Asm[cur][(wr * 32 + m * 16 + lrow) * BK +
                                                     (((kk * 4 + lhi) ^ swz) * 8)];
            #pragma unroll
            for (int n = 0; n < 2; ++n)
                b[kk][n] = *(const bf16x8*)&Bsm[cur][(wc * 32 + n * 16 + lrow) * BK +
                                                     (((kk * 4 + lhi) ^ swz) * 8)];
        }
        #pragma unroll
        for (int kk = 0; kk < 2; ++kk)
            #pragma unroll
            for (int m = 0; m < 2; ++m)
                #pragma unroll
                for (int n = 0; n < 2; ++n)
                    acc[m][n] = __builtin_amdgcn_mfma_f32_16x16x32_bf16(
                        a[kk][m], b[kk][n], acc[m][n], 0, 0, 0);

        __syncthreads();
    }
#undef STAGE

    int crow0 = bm0 + wr * 32 + lhi * 4;
    #pragma unroll
    for (int n = 0; n < 2; ++n) {
        int col = bn0 + wc * 32 + n * 16 + lrow;
        #pragma unroll
        for (int m = 0; m < 2; ++m)
            #pragma unroll
            for (int r = 0; r < 4; ++r)
                Ct[(size_t)(crow0 + m * 16 + r) * O_DIM + col] = acc[m][n][r];
    }
}

// ---------------------------------------------------------------------------
// Reduce: out = out(partial0) [+ p1] + bias.  24 MB traffic ≈ 4 us.
// ---------------------------------------------------------------------------
__global__ __launch_bounds__(256) void reduce_kernel(
    float* __restrict__ out, const float* __restrict__ p1,
    const float* __restrict__ bias, int nphase)
{
    const int total4 = (B_DIM * O_DIM) / 4;
    int stride = gridDim.x * blockDim.x;
    for (int q = blockIdx.x * blockDim.x + threadIdx.x; q < total4; q += stride) {
        float4 v = ((const float4*)out)[q];
        float4 b = ((const float4*)bias)[q & (O_DIM / 4 - 1)];
        if (nphase == 2) {
            float4 w = ((const float4*)p1)[q];
            v.x += w.x; v.y += w.y; v.z += w.z; v.w += w.w;
        }
        v.x += b.x; v.y += b.y; v.z += b.z; v.w += b.w;
        ((float4*)out)[q] = v;
    }
}

extern "C" void kernel_launch(void* const* d_in, const int* in_sizes, int n_in,
                              void* d_out, int out_size, void* d_ws, size_t ws_size,
                              hipStream_t stream) {
    const float* x    = (const float*)d_in[0];
    const float* wts  = (const float*)d_in[1];
    const float* bias = (const float*)d_in[2];
    const float* pb   = (const float*)d_in[3];
    const float* pf   = (const float*)d_in[4];
    const float* pp   = (const float*)d_in[5];
    const float* un   = (const float*)d_in[6];
    float* out = (float*)d_out;

    unsigned short* wm = (unsigned short*)d_ws;              // 32 MB bf16 masked W
    unsigned short* xb = wm + (size_t)O_DIM * I_DIM;         // 4 MB bf16 x
    size_t p1_off = ((size_t)O_DIM * I_DIM + (size_t)B_DIM * I_DIM) * 2;
    float* p1 = (float*)((char*)d_ws + p1_off);              // 8 MB f32 partial

    int nphase = (ws_size >= p1_off + (size_t)B_DIM * O_DIM * 4) ? 2 : 1;

    mask_kernel<<<2048, 256, 0, stream>>>(wts, pb, pf, pp, un, wm);
    cvt_kernel<<<512, 256, 0, stream>>>(x, xb);
    gemm_kernel<<<dim3(512 * nphase), 256, 0, stream>>>(xb, wm, out, p1, nphase);
    reduce_kernel<<<2048, 256, 0, stream>>>(out, p1, bias, nphase);
}